// Round 9
// baseline (36.911 us; speedup 1.0000x reference)
//
#include <hip/hip_runtime.h>

#define B_MOL 64
#define MAXN 28
#define BATCH 7                         // atoms per block
#define NGRP 4                          // 28/7 groups per molecule
#define NSPEC 4
#define NRS2 24
#define NRS3 20
#define NPAIR 10
#define NCOMB 378                       // 28*27/2 fixed (j<k) combos
#define SPAIR_CAP 408                   // 378 + 10 buckets * 3 pad
#define REP2_LEN (NSPEC * NRS2)         // 96
#define REP3_LEN (NPAIR * NRS3 * 2)     // 400
#define OUT_LEN (REP2_LEN + REP3_LEN)   // 496
#define NBIN3 (NPAIR * NRS3)            // 200
#define RCUT 8.0f
#define ETA2 0.32f
#define ETA3 2.7f
#define LOG2E 1.4426950408889634f
#define LN2F 0.6931471805599453f
// sqrt(2.7/pi)*13.4 computed in double, cast to f32
#define W3 12.4225783348083f

#define PAD4(c) (((c) + 3) & ~3)

// hardware transcendentals (raw gfx950 instructions, no libm namespace)
__device__ __forceinline__ float hexp2(float x) { return __builtin_amdgcn_exp2f(x); }
__device__ __forceinline__ float hlog2(float x) { return __builtin_amdgcn_logf(x); }
__device__ __forceinline__ float hrcp(float x)  { return __builtin_amdgcn_rcpf(x); }
__device__ __forceinline__ float hrsq(float x)  { return __builtin_amdgcn_rsqf(x); }
// cos(2*pi*t), t in revolutions
__device__ __forceinline__ float hcos_rev(float t) { return __builtin_amdgcn_cosf(t); }

// compile-time (j,k) pair table, j<k<28, packed (j<<8)|k
struct PairTab { unsigned short jk[NCOMB]; };
static constexpr PairTab make_tab() {
    PairTab t{};
    int idx = 0;
    for (int j = 0; j < MAXN; ++j)
        for (int k = j + 1; k < MAXN; ++k)
            t.jk[idx++] = (unsigned short)((j << 8) | k);
    return t;
}
__constant__ PairTab PT = make_tab();

__global__ __launch_bounds__(256) void fchl_kernel(
    const float* __restrict__ X,      // [B][MAXN][3]
    const float* __restrict__ Z,      // [B][MAXN]
    const int* __restrict__ counts,   // [B]
    float* __restrict__ out)          // [B][MAXN][OUT_LEN]
{
    const int blk = blockIdx.x;
    const int b  = blk >> 2;           // molecule
    const int i0 = (blk & 3) * BATCH;  // first atom of this block's group
    const int tid = threadIdx.x;
    const int cnt = counts[b];

    __shared__ float s_xyz[MAXN * 3];
    __shared__ int   sspec[MAXN];
    __shared__ unsigned char s_win[BATCH][MAXN];
    __shared__ float s_rm[BATCH][MAXN], s_fcm[BATCH][MAXN];
    __shared__ float s_mu[BATCH][MAXN], s_i2[BATCH][MAXN], s_pf[BATCH][MAXN];
    __shared__ int   cntP[BATCH][NPAIR], curP[BATCH][NPAIR];
    __shared__ signed char s_tag[BATCH][NCOMB];
    __shared__ float4 s_pair[BATCH][SPAIR_CAP];

    // ---- P1: zero pair buffer + counters; coords to LDS; spec decode;
    //          per-(a,j) neighbor quantities (196 fully parallel heavy items) ----
    {
        const float4 z4 = make_float4(0.f, 0.f, 0.f, 0.f);
        float4* sp = &s_pair[0][0];
        for (int t = tid; t < BATCH * SPAIR_CAP; t += 256) sp[t] = z4;  // pad slots stay 0
        int* cp = &cntP[0][0];
        int* up = &curP[0][0];
        for (int t = tid; t < BATCH * NPAIR; t += 256) { cp[t] = 0; up[t] = 0; }
    }
    if (tid < MAXN * 3) s_xyz[tid] = X[b * (MAXN * 3) + tid];   // coalesced, consumed post-bar-A
    if (tid >= 196 && tid < 196 + MAXN) {
        int j = tid - 196;
        float z = Z[b * MAXN + j];
        int s = -1;
        if (z == 1.0f) s = 0;
        else if (z == 6.0f) s = 1;
        else if (z == 7.0f) s = 2;
        else if (z == 8.0f) s = 3;
        sspec[j] = s;
    }
    if (tid < BATCH * MAXN) {          // 196 items
        const int a = tid / MAXN;
        const int j = tid - a * MAXN;
        const int i = i0 + a;
        const float* Xb = X + b * (MAXN * 3);
        float xi = Xb[i * 3 + 0], yi = Xb[i * 3 + 1], zi = Xb[i * 3 + 2];
        float xj = Xb[j * 3 + 0], yj = Xb[j * 3 + 1], zj = Xb[j * 3 + 2];
        float dx = xi - xj, dy = yi - yj, dz = zi - zj;
        float r = sqrtf(dx * dx + dy * dy + dz * dz);
        bool w = (i < cnt) && (j < cnt) && (j != i) && (r < RCUT);
        s_win[a][j] = w ? 1 : 0;
        if (w) {
            // fc = 0.5*(cos(pi*r/8)+1) = 0.5*(cos(2pi * r/16)+1)
            float fc = 0.5f * (hcos_rev(r * (1.0f / 16.0f)) + 1.0f);
            float ln = LN2F * hlog2(1.0f + ETA2 * hrcp(r * r));
            float lr = LN2F * hlog2(r);
            s_rm[a][j] = r;
            s_fcm[a][j] = fc;
            s_mu[a][j] = lr - 0.5f * ln;
            s_i2[a][j] = LOG2E / (2.0f * ln);
            s_pf[a][j] = fc * hexp2(-1.8f * hlog2(r)) * hrsq(ln);  // fc*r^-1.8/sqrt(ln)
        } else {
            s_rm[a][j] = 1.0f; s_fcm[a][j] = 0.0f; s_mu[a][j] = 0.0f;
            s_i2[a][j] = 1.0f; s_pf[a][j] = 0.0f;
        }
    }
    __syncthreads();   // bar A

    // ---- P2a: histogram + tag cache over 7*378 = 2646 combos ----
    for (int t = tid; t < BATCH * NCOMB; t += 256) {
        int a = t / NCOMB;
        int idx = t - a * NCOMB;
        int jk = PT.jk[idx];
        int j = jk >> 8, k = jk & 255;
        int tg = -1;
        if (s_win[a][j] && s_win[a][k]) {
            int pj = sspec[j], pk = sspec[k];
            int pp = min(pj, pk), q = max(pj, pk);
            tg = pp * NSPEC - (pp * (pp - 1)) / 2 + (q - pp);
            atomicAdd(&cntP[a][tg], 1);
        }
        s_tag[a][idx] = (signed char)tg;
    }
    __syncthreads();   // bar B

    // ---- P2b: geometry + sorted scatter (padded bucket bases) ----
    for (int t = tid; t < BATCH * NCOMB; t += 256) {
        int a = t / NCOMB;
        int idx = t - a * NCOMB;
        int tg = s_tag[a][idx];
        if (tg < 0) continue;
        int jk = PT.jk[idx];
        int j = jk >> 8, k = jk & 255;

        float rij = s_rm[a][j], rik = s_rm[a][k];
        float dx = s_xyz[j * 3 + 0] - s_xyz[k * 3 + 0];
        float dy = s_xyz[j * 3 + 1] - s_xyz[k * 3 + 1];
        float dz = s_xyz[j * 3 + 2] - s_xyz[k * 3 + 2];
        float rjk = sqrtf(dx * dx + dy * dy + dz * dz);

        float rij2 = rij * rij, rik2 = rik * rik, rjk2 = rjk * rjk;
        float cos_i = (rij2 + rik2 - rjk2) * 0.5f * hrcp(rij * rik);
        float cos_j = (rij2 + rjk2 - rik2) * 0.5f * hrcp(rij * rjk);
        float cos_k = (rik2 + rjk2 - rij2) * 0.5f * hrcp(rik * rjk);

        float atm = (1.0f + 3.0f * cos_i * cos_j * cos_k)
                    * hexp2(-0.57f * hlog2(rij * rik * rjk));
        float w = W3 * atm * s_fcm[a][j] * s_fcm[a][k];

        float c = fminf(fmaxf(cos_i, -1.0f), 1.0f);
        float sn = sqrtf(fminf(fmaxf(1.0f - c * c, 1e-12f), 1.0f));

        int bs = 0;
        #pragma unroll
        for (int q = 0; q < NPAIR - 1; ++q) bs += (q < tg) ? PAD4(cntP[a][q]) : 0;
        int slot = bs + atomicAdd(&curP[a][tg], 1);
        s_pair[a][slot] = make_float4(0.5f * (rij + rik), 2.0f * c * w, 2.0f * sn * w, 0.0f);
    }
    __syncthreads();   // bar C

    // ---- tail: 1400 gather bins + 672 two-body outputs over 256 threads ----
    const int base_atom = b * MAXN + i0;
    for (int t = tid; t < BATCH * (NBIN3 + REP2_LEN); t += 256) {
        if (t < BATCH * NBIN3) {
            int a = t / NBIN3;
            int rem = t - a * NBIN3;
            int P = rem / NRS3, l = rem - P * NRS3;
            const float rs = 0.4f * (float)(l + 1);
            int s0 = 0;
            #pragma unroll
            for (int q = 0; q < NPAIR - 1; ++q) s0 += (q < P) ? PAD4(cntP[a][q]) : 0;
            const int trip = PAD4(cntP[a][P]);
            float acc0 = 0.0f, acc1 = 0.0f;
            const float4* row = s_pair[a];
            for (int s = s0; s < s0 + trip; s += 4) {
                float4 p0 = row[s + 0];
                float4 p1 = row[s + 1];
                float4 p2 = row[s + 2];
                float4 p3 = row[s + 3];
                float d0 = p0.x - rs, d1 = p1.x - rs, d2 = p2.x - rs, d3 = p3.x - rs;
                float e0 = hexp2(-(ETA3 * LOG2E) * d0 * d0);
                float e1 = hexp2(-(ETA3 * LOG2E) * d1 * d1);
                float e2 = hexp2(-(ETA3 * LOG2E) * d2 * d2);
                float e3 = hexp2(-(ETA3 * LOG2E) * d3 * d3);
                acc0 += p0.y * e0 + p1.y * e1 + p2.y * e2 + p3.y * e3;
                acc1 += p0.z * e0 + p1.z * e1 + p2.z * e2 + p3.z * e3;
            }
            float* orow = out + (size_t)(base_atom + a) * OUT_LEN;
            orow[REP2_LEN + P * (NRS3 * 2) + l * 2 + 0] = acc0;
            orow[REP2_LEN + P * (NRS3 * 2) + l * 2 + 1] = acc1;
        } else {
            int t2 = t - BATCH * NBIN3;
            int a = t2 / REP2_LEN;
            int rem = t2 - a * REP2_LEN;
            int sp = rem / NRS2, m = rem - sp * NRS2;
            const float rs2 = (float)(m + 1) * (8.0f / 24.0f);
            const float lrs2 = LN2F * hlog2(rs2);
            const float nrm = 0.3989422804014327f / rs2;   // 1/(sqrt(2pi)*rs2)
            float acc = 0.0f;
            #pragma unroll 4
            for (int j = 0; j < MAXN; ++j) {
                float d = lrs2 - s_mu[a][j];
                float v = s_pf[a][j] * hexp2(-d * d * s_i2[a][j]);   // pf=0 if !win
                acc += (sspec[j] == sp) ? v : 0.0f;
            }
            float* orow = out + (size_t)(base_atom + a) * OUT_LEN;
            orow[sp * NRS2 + m] = acc * nrm;
        }
    }
}

extern "C" void kernel_launch(void* const* d_in, const int* in_sizes, int n_in,
                              void* d_out, int out_size, void* d_ws, size_t ws_size,
                              hipStream_t stream) {
    const float* X = (const float*)d_in[0];
    const float* Z = (const float*)d_in[1];
    // d_in[2] = atomIDs, d_in[3] = molIDs (unused by reference math)
    const int* counts = (const int*)d_in[4];
    float* out = (float*)d_out;

    dim3 grid(B_MOL * NGRP);   // 256 blocks: one per (molecule, 7-atom group)
    dim3 block(256);
    hipLaunchKernelGGL(fchl_kernel, grid, block, 0, stream, X, Z, counts, out);
}

// Round 10
// 18.047 us; speedup vs baseline: 2.0453x; 2.0453x over previous
//
#include <hip/hip_runtime.h>

#define B_MOL 64
#define MAXN 28
#define NSPEC 4
#define NRS2 24
#define NRS3 20
#define NPAIR 10
#define NCOMB 378                       // 28*27/2 fixed (j<k) combos
#define SPAIR_CAP 408                   // 378 + 10 buckets * 3 pad
#define REP2_LEN (NSPEC * NRS2)         // 96
#define REP3_LEN (NPAIR * NRS3 * 2)     // 400
#define OUT_LEN (REP2_LEN + REP3_LEN)   // 496
#define NBIN3 (NPAIR * NRS3)            // 200
#define RCUT 8.0f
#define ETA2 0.32f
#define ETA3 2.7f
#define LOG2E 1.4426950408889634f
#define LN2F 0.6931471805599453f
// sqrt(2.7/pi)*13.4 computed in double, cast to f32
#define W3 12.4225783348083f

#define PAD4(c) (((c) + 3) & ~3)

// hardware transcendentals (raw gfx950 instructions, no libm namespace)
__device__ __forceinline__ float hexp2(float x) { return __builtin_amdgcn_exp2f(x); }
__device__ __forceinline__ float hlog2(float x) { return __builtin_amdgcn_logf(x); }
__device__ __forceinline__ float hrcp(float x)  { return __builtin_amdgcn_rcpf(x); }
__device__ __forceinline__ float hrsq(float x)  { return __builtin_amdgcn_rsqf(x); }
// cos(2*pi*t), t in revolutions
__device__ __forceinline__ float hcos_rev(float t) { return __builtin_amdgcn_cosf(t); }

// compile-time (j,k) pair table, j<k<28, packed (j<<8)|k
struct PairTab { unsigned short jk[NCOMB]; };
static constexpr PairTab make_tab() {
    PairTab t{};
    int idx = 0;
    for (int j = 0; j < MAXN; ++j)
        for (int k = j + 1; k < MAXN; ++k)
            t.jk[idx++] = (unsigned short)((j << 8) | k);
    return t;
}
__constant__ PairTab PT = make_tab();

// padded-bucket prefix: sum of PAD4(c_q) for q < t, all compile-time-indexed
__device__ __forceinline__ int bucket_prefix(int t, int n0, int n1, int n2, int n3) {
    int c0 = (n0 * (n0 - 1)) >> 1;
    int c1 = n0 * n1;
    int c2 = n0 * n2;
    int c3 = n0 * n3;
    int c4 = (n1 * (n1 - 1)) >> 1;
    int c5 = n1 * n2;
    int c6 = n1 * n3;
    int c7 = (n2 * (n2 - 1)) >> 1;
    int c8 = n2 * n3;
    int c9 = (n3 * (n3 - 1)) >> 1;
    int s = 0;
    s += (t > 0) ? PAD4(c0) : 0;
    s += (t > 1) ? PAD4(c1) : 0;
    s += (t > 2) ? PAD4(c2) : 0;
    s += (t > 3) ? PAD4(c3) : 0;
    s += (t > 4) ? PAD4(c4) : 0;
    s += (t > 5) ? PAD4(c5) : 0;
    s += (t > 6) ? PAD4(c6) : 0;
    s += (t > 7) ? PAD4(c7) : 0;
    s += (t > 8) ? PAD4(c8) : 0;
    s += (t > 9) ? PAD4(c9) : 0;
    return s;
}

__global__ __launch_bounds__(256) void fchl_kernel(
    const float* __restrict__ X,      // [B][MAXN][3]
    const float* __restrict__ Z,      // [B][MAXN]
    const int* __restrict__ counts,   // [B]
    float* __restrict__ out)          // [B][MAXN][OUT_LEN]
{
    const int i = blockIdx.x;      // atom index within molecule
    const int b = blockIdx.y;      // molecule
    const int tid = threadIdx.x;
    const int cnt = counts[b];

    __shared__ float sx[MAXN], sy[MAXN], szc[MAXN];
    __shared__ int   s_win[MAXN];
    __shared__ float s_r[MAXN], s_fc[MAXN];
    __shared__ float s_mu[MAXN + 1], s_i2ln[MAXN + 1], s_pref[MAXN + 1];  // [28] = dummy
    __shared__ int   sspec[MAXN];
    __shared__ int   curP[NPAIR];
    __shared__ int   cntSp[NSPEC];
    __shared__ int   spList[NSPEC][32];          // 32 cap so padded reads stay in-row
    __shared__ float4 s_pair[SPAIR_CAP];

    float* orow = out + (size_t)(b * MAXN + i) * OUT_LEN;

    // ---- P1: zero pair buffer + counters; per-j quantities; species lists ----
    {
        const float4 z4 = make_float4(0.f, 0.f, 0.f, 0.f);
        for (int t = tid; t < SPAIR_CAP; t += 256) s_pair[t] = z4;   // pad slots stay 0
    }
    if (tid >= 28 && tid < 28 + NSPEC) cntSp[tid - 28] = 0;        // wave 0, program-order before its atomics
    if (tid >= 64 && tid < 64 + NPAIR) curP[tid - 64] = 0;          // wave 1
    if (tid == MAXN) { s_pref[MAXN] = 0.f; s_mu[MAXN] = 0.f; s_i2ln[MAXN] = 1.f; }  // dummy atom
    if (tid < MAXN) {
        const int j = tid;
        float xi = X[(b * MAXN + i) * 3 + 0];   // broadcast loads
        float yi = X[(b * MAXN + i) * 3 + 1];
        float zi = X[(b * MAXN + i) * 3 + 2];
        float xj = X[(b * MAXN + j) * 3 + 0];
        float yj = X[(b * MAXN + j) * 3 + 1];
        float zj = X[(b * MAXN + j) * 3 + 2];
        sx[j] = xj; sy[j] = yj; szc[j] = zj;
        float z = Z[b * MAXN + j];
        int s = -1;
        if (z == 1.0f) s = 0;
        else if (z == 6.0f) s = 1;
        else if (z == 7.0f) s = 2;
        else if (z == 8.0f) s = 3;
        sspec[j] = s;

        float dx = xi - xj, dy = yi - yj, dz = zi - zj;
        float r = sqrtf(dx * dx + dy * dy + dz * dz);
        bool w = (i < cnt) && (j < cnt) && (j != i) && (r < RCUT);
        s_win[j] = w ? 1 : 0;
        if (w) {
            // fc = 0.5*(cos(pi*r/8)+1) = 0.5*(cos(2pi * r/16)+1)
            float fc = 0.5f * (hcos_rev(r * (1.0f / 16.0f)) + 1.0f);
            float ln = LN2F * hlog2(1.0f + ETA2 * hrcp(r * r));
            float lr = LN2F * hlog2(r);
            s_r[j] = r;
            s_fc[j] = fc;
            s_mu[j] = lr - 0.5f * ln;
            s_i2ln[j] = LOG2E / (2.0f * ln);
            s_pref[j] = fc * hexp2(-1.8f * hlog2(r)) * hrsq(ln);  // fc*r^-1.8/sqrt(ln)
            int pos = atomicAdd(&cntSp[s], 1);                    // same wave, after zeroing above
            spList[s][pos] = j;
        } else {
            s_r[j] = 1.0f; s_fc[j] = 0.0f; s_mu[j] = 0.0f;
            s_i2ln[j] = 1.0f; s_pref[j] = 0.0f;
        }
    }
    __syncthreads();   // bar A

    // ---- P2: single combo pass — geometry + sorted scatter
    //      (bucket bases analytically from species counts; no histogram pass) ----
    const int n0 = cntSp[0], n1 = cntSp[1], n2 = cntSp[2], n3 = cntSp[3];
    for (int idx = tid; idx < NCOMB; idx += 256) {
        int jk = PT.jk[idx];
        int j = jk >> 8, k = jk & 255;
        if (!(s_win[j] && s_win[k])) continue;

        float rij = s_r[j], rik = s_r[k];
        float dx = sx[j] - sx[k], dy = sy[j] - sy[k], dz = szc[j] - szc[k];
        float rjk = sqrtf(dx * dx + dy * dy + dz * dz);

        float rij2 = rij * rij, rik2 = rik * rik, rjk2 = rjk * rjk;
        float cos_i = (rij2 + rik2 - rjk2) * 0.5f * hrcp(rij * rik);
        float cos_j = (rij2 + rjk2 - rik2) * 0.5f * hrcp(rij * rjk);
        float cos_k = (rik2 + rjk2 - rij2) * 0.5f * hrcp(rik * rjk);

        float atm = (1.0f + 3.0f * cos_i * cos_j * cos_k)
                    * hexp2(-0.57f * hlog2(rij * rik * rjk));
        float w = W3 * atm * s_fc[j] * s_fc[k];

        float c = fminf(fmaxf(cos_i, -1.0f), 1.0f);
        float sn = sqrtf(fminf(fmaxf(1.0f - c * c, 1e-12f), 1.0f));

        int pj = sspec[j], pk = sspec[k];
        int pp = min(pj, pk), q = max(pj, pk);
        int tg = pp * NSPEC - (pp * (pp - 1)) / 2 + (q - pp);

        int bs = bucket_prefix(tg, n0, n1, n2, n3);
        int slot = bs + atomicAdd(&curP[tg], 1);
        s_pair[slot] = make_float4(0.5f * (rij + rik), 2.0f * c * w, 2.0f * sn * w, 0.0f);
    }
    __syncthreads();   // bar B

    // ---- tail: tids 0-199 gather bins (unroll-4, padded trip);
    //            tids 200-255 two-body (<=2 rounds, unroll-4 w/ dummy idx) ----
    if (tid < NBIN3) {
        const int P = tid / NRS3;
        const int l = tid % NRS3;
        const float rs = 0.4f * (float)(l + 1);
        const int s0 = bucket_prefix(P, n0, n1, n2, n3);
        const int s1 = bucket_prefix(P + 1, n0, n1, n2, n3);   // s1-s0 = PAD4(cnt[P])
        float acc0 = 0.0f, acc1 = 0.0f;
        for (int s = s0; s < s1; s += 4) {
            float4 p0 = s_pair[s + 0];
            float4 p1 = s_pair[s + 1];
            float4 p2 = s_pair[s + 2];
            float4 p3 = s_pair[s + 3];
            float d0 = p0.x - rs, d1 = p1.x - rs, d2 = p2.x - rs, d3 = p3.x - rs;
            float e0 = hexp2(-(ETA3 * LOG2E) * d0 * d0);
            float e1 = hexp2(-(ETA3 * LOG2E) * d1 * d1);
            float e2 = hexp2(-(ETA3 * LOG2E) * d2 * d2);
            float e3 = hexp2(-(ETA3 * LOG2E) * d3 * d3);
            acc0 += p0.y * e0 + p1.y * e1 + p2.y * e2 + p3.y * e3;
            acc1 += p0.z * e0 + p1.z * e1 + p2.z * e2 + p3.z * e3;
        }
        orow[REP2_LEN + P * (NRS3 * 2) + l * 2 + 0] = acc0;
        orow[REP2_LEN + P * (NRS3 * 2) + l * 2 + 1] = acc1;
    } else {
        for (int t2 = tid - 200; t2 < REP2_LEN; t2 += 56) {
            const int sp = t2 / NRS2;
            const int m = t2 % NRS2;
            const float rs2 = (float)(m + 1) * (8.0f / 24.0f);
            const float lrs2 = LN2F * hlog2(rs2);
            const float nrm = 0.3989422804014327f / rs2;   // 1/(sqrt(2pi)*rs2)
            const int n = cntSp[sp];
            const int trip = PAD4(n);
            float acc = 0.0f;
            for (int c = 0; c < trip; c += 4) {
                int r0 = spList[sp][c + 0];
                int r1 = spList[sp][c + 1];
                int r2 = spList[sp][c + 2];
                int r3 = spList[sp][c + 3];
                int j0 = (c + 0 < n) ? r0 : MAXN;    // select before address use
                int j1 = (c + 1 < n) ? r1 : MAXN;
                int j2 = (c + 2 < n) ? r2 : MAXN;
                int j3 = (c + 3 < n) ? r3 : MAXN;
                float d0 = lrs2 - s_mu[j0], d1 = lrs2 - s_mu[j1];
                float d2 = lrs2 - s_mu[j2], d3 = lrs2 - s_mu[j3];
                acc += s_pref[j0] * hexp2(-d0 * d0 * s_i2ln[j0])
                     + s_pref[j1] * hexp2(-d1 * d1 * s_i2ln[j1])
                     + s_pref[j2] * hexp2(-d2 * d2 * s_i2ln[j2])
                     + s_pref[j3] * hexp2(-d3 * d3 * s_i2ln[j3]);
            }
            orow[sp * NRS2 + m] = acc * nrm;
        }
    }
}

extern "C" void kernel_launch(void* const* d_in, const int* in_sizes, int n_in,
                              void* d_out, int out_size, void* d_ws, size_t ws_size,
                              hipStream_t stream) {
    const float* X = (const float*)d_in[0];
    const float* Z = (const float*)d_in[1];
    // d_in[2] = atomIDs, d_in[3] = molIDs (unused by reference math)
    const int* counts = (const int*)d_in[4];
    float* out = (float*)d_out;

    dim3 grid(MAXN, B_MOL);   // one block per (atom i, molecule b)
    dim3 block(256);
    hipLaunchKernelGGL(fchl_kernel, grid, block, 0, stream, X, Z, counts, out);
}

// Round 11
// 17.291 us; speedup vs baseline: 2.1346x; 1.0437x over previous
//
#include <hip/hip_runtime.h>

#define B_MOL 64
#define MAXN 28
#define NSPEC 4
#define NRS2 24
#define NRS3 20
#define NPAIR 10
#define NCOMB 378                       // 28*27/2 fixed (j<k) combos
#define SPAIR_CAP 408                   // 378 + 10 buckets * 3 pad
#define REP2_LEN (NSPEC * NRS2)         // 96
#define REP3_LEN (NPAIR * NRS3 * 2)     // 400
#define OUT_LEN (REP2_LEN + REP3_LEN)   // 496
#define NBIN3 (NPAIR * NRS3)            // 200
#define RCUT 8.0f
#define ETA2 0.32f
#define ETA3 2.7f
#define LOG2E 1.4426950408889634f
#define LN2F 0.6931471805599453f
// sqrt(2.7/pi)*13.4 computed in double, cast to f32
#define W3 12.4225783348083f

#define PAD4(c) (((c) + 3) & ~3)

// hardware transcendentals (raw gfx950 instructions, no libm namespace)
__device__ __forceinline__ float hexp2(float x) { return __builtin_amdgcn_exp2f(x); }
__device__ __forceinline__ float hlog2(float x) { return __builtin_amdgcn_logf(x); }
__device__ __forceinline__ float hrcp(float x)  { return __builtin_amdgcn_rcpf(x); }
__device__ __forceinline__ float hrsq(float x)  { return __builtin_amdgcn_rsqf(x); }
// cos(2*pi*t), t in revolutions
__device__ __forceinline__ float hcos_rev(float t) { return __builtin_amdgcn_cosf(t); }

// compile-time (j,k) pair table, j<k<28, packed (j<<8)|k
struct PairTab { unsigned short jk[NCOMB]; };
static constexpr PairTab make_tab() {
    PairTab t{};
    int idx = 0;
    for (int j = 0; j < MAXN; ++j)
        for (int k = j + 1; k < MAXN; ++k)
            t.jk[idx++] = (unsigned short)((j << 8) | k);
    return t;
}
__constant__ PairTab PT = make_tab();

// padded-bucket prefix: sum of PAD4(c_q) for q < t, all compile-time-indexed
__device__ __forceinline__ int bucket_prefix(int t, int n0, int n1, int n2, int n3) {
    int c0 = (n0 * (n0 - 1)) >> 1;
    int c1 = n0 * n1;
    int c2 = n0 * n2;
    int c3 = n0 * n3;
    int c4 = (n1 * (n1 - 1)) >> 1;
    int c5 = n1 * n2;
    int c6 = n1 * n3;
    int c7 = (n2 * (n2 - 1)) >> 1;
    int c8 = n2 * n3;
    int c9 = (n3 * (n3 - 1)) >> 1;
    int s = 0;
    s += (t > 0) ? PAD4(c0) : 0;
    s += (t > 1) ? PAD4(c1) : 0;
    s += (t > 2) ? PAD4(c2) : 0;
    s += (t > 3) ? PAD4(c3) : 0;
    s += (t > 4) ? PAD4(c4) : 0;
    s += (t > 5) ? PAD4(c5) : 0;
    s += (t > 6) ? PAD4(c6) : 0;
    s += (t > 7) ? PAD4(c7) : 0;
    s += (t > 8) ? PAD4(c8) : 0;
    s += (t > 9) ? PAD4(c9) : 0;
    return s;
}

__global__ __launch_bounds__(256) void fchl_kernel(
    const float* __restrict__ X,      // [B][MAXN][3]
    const float* __restrict__ Z,      // [B][MAXN]
    const int* __restrict__ counts,   // [B]
    float* __restrict__ out)          // [B][MAXN][OUT_LEN]
{
    const int i = blockIdx.x;      // atom index within molecule
    const int b = blockIdx.y;      // molecule
    const int tid = threadIdx.x;
    const int cnt = counts[b];

    __shared__ float sx[MAXN], sy[MAXN], szc[MAXN];
    __shared__ int   s_win[MAXN];
    __shared__ float s_r[MAXN], s_fc[MAXN];
    __shared__ float s_mu[MAXN + 1], s_i2ln[MAXN + 1], s_pref[MAXN + 1];  // [28] = dummy
    __shared__ int   sspec[MAXN];
    __shared__ int   curP[NPAIR];
    __shared__ int   cntSp[NSPEC];
    __shared__ int   spList[NSPEC][32];          // 32 cap so padded reads stay in-row
    __shared__ float4 s_pair[SPAIR_CAP];
    __shared__ float2 s_part[2][NBIN3];          // per-bin half-accumulators

    float* orow = out + (size_t)(b * MAXN + i) * OUT_LEN;

    // ---- P1: zero pair buffer + counters; per-j quantities; species lists ----
    {
        const float4 z4 = make_float4(0.f, 0.f, 0.f, 0.f);
        for (int t = tid; t < SPAIR_CAP; t += 256) s_pair[t] = z4;   // pad slots stay 0
    }
    if (tid >= 28 && tid < 28 + NSPEC) cntSp[tid - 28] = 0;        // wave 0, program-order before its atomics
    if (tid >= 64 && tid < 64 + NPAIR) curP[tid - 64] = 0;          // wave 1
    if (tid == MAXN) { s_pref[MAXN] = 0.f; s_mu[MAXN] = 0.f; s_i2ln[MAXN] = 1.f; }  // dummy atom
    if (tid < MAXN) {
        const int j = tid;
        float xi = X[(b * MAXN + i) * 3 + 0];   // broadcast loads
        float yi = X[(b * MAXN + i) * 3 + 1];
        float zi = X[(b * MAXN + i) * 3 + 2];
        float xj = X[(b * MAXN + j) * 3 + 0];
        float yj = X[(b * MAXN + j) * 3 + 1];
        float zj = X[(b * MAXN + j) * 3 + 2];
        sx[j] = xj; sy[j] = yj; szc[j] = zj;
        float z = Z[b * MAXN + j];
        int s = -1;
        if (z == 1.0f) s = 0;
        else if (z == 6.0f) s = 1;
        else if (z == 7.0f) s = 2;
        else if (z == 8.0f) s = 3;
        sspec[j] = s;

        float dx = xi - xj, dy = yi - yj, dz = zi - zj;
        float r = sqrtf(dx * dx + dy * dy + dz * dz);
        bool w = (i < cnt) && (j < cnt) && (j != i) && (r < RCUT);
        s_win[j] = w ? 1 : 0;
        if (w) {
            // fc = 0.5*(cos(pi*r/8)+1) = 0.5*(cos(2pi * r/16)+1)
            float fc = 0.5f * (hcos_rev(r * (1.0f / 16.0f)) + 1.0f);
            float l2r = hlog2(r);                                  // reused 3x
            float ln = LN2F * hlog2(1.0f + ETA2 * hrcp(r * r));
            float lr = LN2F * l2r;
            s_r[j] = r;
            s_fc[j] = fc;
            s_mu[j] = lr - 0.5f * ln;
            s_i2ln[j] = LOG2E / (2.0f * ln);
            s_pref[j] = fc * hexp2(-1.8f * l2r) * hrsq(ln);        // fc*r^-1.8/sqrt(ln)
            int pos = atomicAdd(&cntSp[s], 1);                     // same wave, after zeroing above
            spList[s][pos] = j;
        } else {
            s_r[j] = 1.0f; s_fc[j] = 0.0f; s_mu[j] = 0.0f;
            s_i2ln[j] = 1.0f; s_pref[j] = 0.0f;
        }
    }
    __syncthreads();   // bar A

    // ---- P2: single combo pass — geometry + sorted scatter
    //      (bucket bases analytically from species counts) ----
    const int n0 = cntSp[0], n1 = cntSp[1], n2 = cntSp[2], n3 = cntSp[3];
    for (int idx = tid; idx < NCOMB; idx += 256) {
        int jk = PT.jk[idx];
        int j = jk >> 8, k = jk & 255;
        if (!(s_win[j] && s_win[k])) continue;

        float rij = s_r[j], rik = s_r[k];
        float dx = sx[j] - sx[k], dy = sy[j] - sy[k], dz = szc[j] - szc[k];
        float rjk = sqrtf(dx * dx + dy * dy + dz * dz);

        float rij2 = rij * rij, rik2 = rik * rik, rjk2 = rjk * rjk;
        float cos_i = (rij2 + rik2 - rjk2) * 0.5f * hrcp(rij * rik);
        float cos_j = (rij2 + rjk2 - rik2) * 0.5f * hrcp(rij * rjk);
        float cos_k = (rik2 + rjk2 - rij2) * 0.5f * hrcp(rik * rjk);

        float atm = (1.0f + 3.0f * cos_i * cos_j * cos_k)
                    * hexp2(-0.57f * hlog2(rij * rik * rjk));
        float w = W3 * atm * s_fc[j] * s_fc[k];

        float c = fminf(fmaxf(cos_i, -1.0f), 1.0f);
        float sn = sqrtf(fminf(fmaxf(1.0f - c * c, 1e-12f), 1.0f));

        int pj = sspec[j], pk = sspec[k];
        int pp = min(pj, pk), q = max(pj, pk);
        int tg = pp * NSPEC - (pp * (pp - 1)) / 2 + (q - pp);

        int bs = bucket_prefix(tg, n0, n1, n2, n3);
        int slot = bs + atomicAdd(&curP[tg], 1);
        s_pair[slot] = make_float4(0.5f * (rij + rik), 2.0f * c * w, 2.0f * sn * w, 0.0f);
    }
    __syncthreads();   // bar B

    // ---- tail: 400 gather half-tasks + 96 two-body over 256 threads ----
    // half-task h: bin = h>>1, half = h&1; processes quads half,half+2,half+4,...
    // round 1: tids 0-255 -> halves 0-255 (bins 0-127, the big buckets)
    // round 2: tids 0-143 -> halves 256-399; tids 144-239 -> two-body (1 task each)
    #pragma unroll 1
    for (int rnd = 0; rnd < 2; ++rnd) {
        int h = (rnd == 0) ? tid : 256 + tid;
        if (rnd == 1 && tid >= 144) break;
        int bin = h >> 1, half = h & 1;
        int P = bin / NRS3, l = bin - P * NRS3;
        const float rs = 0.4f * (float)(l + 1);
        const int s0 = bucket_prefix(P, n0, n1, n2, n3);
        const int s1 = bucket_prefix(P + 1, n0, n1, n2, n3);   // s1-s0 = PAD4(cnt[P])
        float acc0 = 0.0f, acc1 = 0.0f;
        for (int s = s0 + half * 4; s < s1; s += 8) {
            float4 p0 = s_pair[s + 0];
            float4 p1 = s_pair[s + 1];
            float4 p2 = s_pair[s + 2];
            float4 p3 = s_pair[s + 3];
            float d0 = p0.x - rs, d1 = p1.x - rs, d2 = p2.x - rs, d3 = p3.x - rs;
            float e0 = hexp2(-(ETA3 * LOG2E) * d0 * d0);
            float e1 = hexp2(-(ETA3 * LOG2E) * d1 * d1);
            float e2 = hexp2(-(ETA3 * LOG2E) * d2 * d2);
            float e3 = hexp2(-(ETA3 * LOG2E) * d3 * d3);
            acc0 += p0.y * e0 + p1.y * e1 + p2.y * e2 + p3.y * e3;
            acc1 += p0.z * e0 + p1.z * e1 + p2.z * e2 + p3.z * e3;
        }
        s_part[half][bin] = make_float2(acc0, acc1);
    }
    if (tid >= 144 && tid < 144 + REP2_LEN) {      // two-body, 1 task/thread
        const int t2 = tid - 144;
        const int sp = t2 / NRS2;
        const int m = t2 % NRS2;
        const float rs2 = (float)(m + 1) * (8.0f / 24.0f);
        const float lrs2 = LN2F * hlog2(rs2);
        const float nrm = 0.3989422804014327f / rs2;   // 1/(sqrt(2pi)*rs2)
        const int n = cntSp[sp];
        const int trip = PAD4(n);
        float acc = 0.0f;
        for (int c = 0; c < trip; c += 4) {
            int r0 = spList[sp][c + 0];
            int r1 = spList[sp][c + 1];
            int r2 = spList[sp][c + 2];
            int r3 = spList[sp][c + 3];
            int j0 = (c + 0 < n) ? r0 : MAXN;    // select before address use
            int j1 = (c + 1 < n) ? r1 : MAXN;
            int j2 = (c + 2 < n) ? r2 : MAXN;
            int j3 = (c + 3 < n) ? r3 : MAXN;
            float d0 = lrs2 - s_mu[j0], d1 = lrs2 - s_mu[j1];
            float d2 = lrs2 - s_mu[j2], d3 = lrs2 - s_mu[j3];
            acc += s_pref[j0] * hexp2(-d0 * d0 * s_i2ln[j0])
                 + s_pref[j1] * hexp2(-d1 * d1 * s_i2ln[j1])
                 + s_pref[j2] * hexp2(-d2 * d2 * s_i2ln[j2])
                 + s_pref[j3] * hexp2(-d3 * d3 * s_i2ln[j3]);
        }
        orow[sp * NRS2 + m] = acc * nrm;
    }
    __syncthreads();   // bar C

    // ---- merge halves + store rep3 (200 threads, 2 stores each) ----
    if (tid < NBIN3) {
        float2 a = s_part[0][tid];
        float2 bb = s_part[1][tid];
        orow[REP2_LEN + tid * 2 + 0] = a.x + bb.x;
        orow[REP2_LEN + tid * 2 + 1] = a.y + bb.y;
    }
}

extern "C" void kernel_launch(void* const* d_in, const int* in_sizes, int n_in,
                              void* d_out, int out_size, void* d_ws, size_t ws_size,
                              hipStream_t stream) {
    const float* X = (const float*)d_in[0];
    const float* Z = (const float*)d_in[1];
    // d_in[2] = atomIDs, d_in[3] = molIDs (unused by reference math)
    const int* counts = (const int*)d_in[4];
    float* out = (float*)d_out;

    dim3 grid(MAXN, B_MOL);   // one block per (atom i, molecule b)
    dim3 block(256);
    hipLaunchKernelGGL(fchl_kernel, grid, block, 0, stream, X, Z, counts, out);
}